// Round 9
// baseline (88.546 us; speedup 1.0000x reference)
//
#include <hip/hip_runtime.h>
#include <hip/hip_bf16.h>

typedef __attribute__((ext_vector_type(8))) unsigned short ushort8;
typedef __attribute__((ext_vector_type(8))) __bf16 bf16x8;
typedef __attribute__((ext_vector_type(4))) float f32x4;
typedef __attribute__((ext_vector_type(4))) unsigned short ushort4v;

__device__ __forceinline__ float lrelu_f(float v){ return v > 0.f ? v : 0.1f*v; }

__device__ __forceinline__ unsigned short f2bf(float v){
  unsigned u = __float_as_uint(v);
  unsigned r = (u + 0x7fffu + ((u>>16)&1u)) >> 16;
  return (unsigned short)r;
}
__device__ __forceinline__ float bf2f(unsigned short u){
  return __uint_as_float(((unsigned)u)<<16);
}

__device__ __forceinline__ void packq(const float* __restrict__ s,
                                      unsigned short* __restrict__ d, int i){
  const float4 v = ((const float4*)s)[i];
  ushort4v o; o.x=f2bf(v.x); o.y=f2bf(v.y); o.z=f2bf(v.z); o.w=f2bf(v.w);
  *(ushort4v*)(d + (size_t)i*4) = o;
}

// ============ one fused pack kernel: all weights -> bf16 ============
__global__ __launch_bounds__(256) void k_pack_all(
  const float* __restrict__ k1_w1, const float* __restrict__ k2_w1,
  const float* __restrict__ p1_w,  const float* __restrict__ p2_w,
  const float* __restrict__ ca1_w1,const float* __restrict__ ca1_w2,
  const float* __restrict__ ca2_w1,const float* __restrict__ ca2_w2,
  const float* __restrict__ deg,   const float* __restrict__ conv1_w,
  const float* __restrict__ conv2_w,
  unsigned short* __restrict__ K1B, unsigned short* __restrict__ K2B,
  unsigned short* __restrict__ P1B, unsigned short* __restrict__ P2B,
  unsigned short* __restrict__ CA1A,unsigned short* __restrict__ CA1B,
  unsigned short* __restrict__ CA2A,unsigned short* __restrict__ CA2B,
  unsigned short* __restrict__ DEGB,unsigned short* __restrict__ DEGT,
  unsigned short* __restrict__ WB1, unsigned short* __restrict__ WB2){
  int i = blockIdx.x*256 + threadIdx.x;
  if (i < 65536){ packq(k1_w1, K1B, i); return; } i -= 65536;
  if (i < 65536){ packq(k2_w1, K2B, i); return; } i -= 65536;
  if (i < 65536){ packq(p1_w,  P1B, i); return; } i -= 65536;
  if (i < 65536){ packq(p2_w,  P2B, i); return; } i -= 65536;
  if (i < 8192){ packq(ca1_w1, CA1A, i); return; } i -= 8192;
  if (i < 8192){ packq(ca1_w2, CA1B, i); return; } i -= 8192;
  if (i < 8192){ packq(ca2_w1, CA2A, i); return; } i -= 8192;
  if (i < 8192){ packq(ca2_w2, CA2B, i); return; } i -= 8192;
  if (i < 65536){ packq(deg, DEGB, i); return; } i -= 65536;
  if (i < 65536){                      // DEGT: bf16 transpose of deg
    const int j = i*4; const int p = j>>9, c = j&511;
    ushort4v o;
    o.x = f2bf(deg[(size_t)(c+0)*512 + p]);
    o.y = f2bf(deg[(size_t)(c+1)*512 + p]);
    o.z = f2bf(deg[(size_t)(c+2)*512 + p]);
    o.w = f2bf(deg[(size_t)(c+3)*512 + p]);
    *(ushort4v*)(DEGT + (size_t)j) = o;
    return;
  } i -= 65536;
  if (i < 589824){                     // WB1: [o][t*512+ci] = w[o][ci*9+t]
    const int o_ = i/1152; const int r4 = (i - o_*1152)*4;
    const int t = r4>>9; const int ci = r4&511;
    const float* s = conv1_w + (size_t)o_*4608;
    ushort4v o;
    o.x = f2bf(s[(ci+0)*9 + t]); o.y = f2bf(s[(ci+1)*9 + t]);
    o.z = f2bf(s[(ci+2)*9 + t]); o.w = f2bf(s[(ci+3)*9 + t]);
    *(ushort4v*)(WB1 + (size_t)o_*4608 + r4) = o;
    return;
  } i -= 589824;
  if (i < 589824){                     // WB2
    const int o_ = i/1152; const int r4 = (i - o_*1152)*4;
    const int t = r4>>9; const int ci = r4&511;
    const float* s = conv2_w + (size_t)o_*4608;
    ushort4v o;
    o.x = f2bf(s[(ci+0)*9 + t]); o.y = f2bf(s[(ci+1)*9 + t]);
    o.z = f2bf(s[(ci+2)*9 + t]); o.w = f2bf(s[(ci+3)*9 + t]);
    *(ushort4v*)(WB2 + (size_t)o_*4608 + r4) = o;
  }
}

// ======= shared 64x64 MFMA GEMM core, 4 waves, dbuf single-barrier =======
__device__ __forceinline__ void gemm64(
    const unsigned short* __restrict__ A, const unsigned short* __restrict__ Bt,
    int m0, int n0, int K, int tid,
    unsigned short* lA, unsigned short* lB, f32x4 acc[2][2]){
  const int wid = tid>>6, lane = tid&63;
  const int srow = tid>>2, skb = tid&3;
  const unsigned short* gA = A  + (size_t)(m0+srow)*K + skb*8;
  const unsigned short* gB = Bt + (size_t)(n0+srow)*K + skb*8;
  const int soff = srow*32 + 8*(skb ^ (srow&3));
  const int wr = (wid>>1)*32, wc = (wid&1)*32;
  const int l15 = lane&15, lkb = lane>>4;
  int aoff[2], boff[2];
  #pragma unroll
  for (int s=0;s<2;s++){
    const int Ra = wr + s*16 + l15;
    aoff[s] = Ra*32 + 8*(lkb ^ (Ra&3));
    const int Rb = wc + s*16 + l15;
    boff[s] = Rb*32 + 8*(lkb ^ (Rb&3));
  }
  const int nst = K>>5;
  ushort8 ra = *(const ushort8*)gA;
  ushort8 rb = *(const ushort8*)gB;
  *(ushort8*)(lA + soff) = ra;
  *(ushort8*)(lB + soff) = rb;
  if (nst > 1){ ra = *(const ushort8*)(gA+32); rb = *(const ushort8*)(gB+32); }
  __syncthreads();
  for (int st=0; st<nst; ++st){
    const int cur = (st&1)*2048;
    bf16x8 af[2], bfr[2];
    #pragma unroll
    for (int s=0;s<2;s++){
      af[s]  = *(const bf16x8*)(lA + cur + aoff[s]);
      bfr[s] = *(const bf16x8*)(lB + cur + boff[s]);
    }
    if (st+1 < nst){
      const int nxt = ((st+1)&1)*2048;
      *(ushort8*)(lA + nxt + soff) = ra;
      *(ushort8*)(lB + nxt + soff) = rb;
      if (st+2 < nst){
        ra = *(const ushort8*)(gA + (size_t)(st+2)*32);
        rb = *(const ushort8*)(gB + (size_t)(st+2)*32);
      }
    }
    #pragma unroll
    for (int mi=0;mi<2;mi++)
      #pragma unroll
      for (int ni=0;ni<2;ni++)
        acc[mi][ni] = __builtin_amdgcn_mfma_f32_16x16x32_bf16(af[mi], bfr[ni], acc[mi][ni], 0,0,0);
    __syncthreads();
  }
}

// ======= fused pre-phase: kern partials + attention maps, one kernel =======
// blocks 0..127: kern branch  (b = bid>>6, i-tile = (bid&63)>>3, j-chunk = bid&7)
//   GEMM 64x64x512 (deg @ kw1^T), then in-register contraction with kw2 ->
//   KP[b][jc][512 c][9 t] partials (summed later by dwconv, deterministic).
// blocks 128..143: att branch (b, p-tile): HID tile in LDS, then ATT = sigmoid.
__global__ __launch_bounds__(256) void k_prep(
    const unsigned short* __restrict__ DEGB, const unsigned short* __restrict__ DEGT,
    const unsigned short* __restrict__ K1B,  const unsigned short* __restrict__ K2B,
    const unsigned short* __restrict__ CA1A, const unsigned short* __restrict__ CA2A,
    const unsigned short* __restrict__ CA1B, const unsigned short* __restrict__ CA2B,
    const float* __restrict__ kw2a, const float* __restrict__ kw2b,
    float* __restrict__ KP1, float* __restrict__ KP2,
    float* __restrict__ ATT1, float* __restrict__ ATT2){
  __shared__ unsigned short lA[4096], lB[4096];
  __shared__ float kp[2][64][9];
  __shared__ unsigned short hid[4096];
  int bid = blockIdx.x;
  const int tid = threadIdx.x;
  const int wid = tid>>6, lane = tid&63;
  const int l15 = lane&15, lkb = lane>>4;

  if (bid < 128){
    const int b  = bid>>6;
    const int r6 = bid&63;
    const int it = r6>>3, jc = r6&7;
    const unsigned short* Bt = b ? K2B : K1B;
    const float* kw2 = b ? kw2b : kw2a;
    float* KP = b ? KP2 : KP1;
    f32x4 acc[2][2] = {};
    gemm64(DEGB, Bt, it*64, jc*64, 512, tid, lA, lB, acc);

    const int wr = (wid>>1)*32, wcl = wid&1;
    const int col0 = wcl*32 + l15, col1 = col0 + 16;
    float w0[9], w1[9];
    #pragma unroll
    for (int t=0;t<9;t++){
      w0[t] = kw2[t*512 + jc*64 + col0];
      w1[t] = kw2[t*512 + jc*64 + col1];
    }
    #pragma unroll
    for (int mi=0;mi<2;mi++)
      #pragma unroll
      for (int r=0;r<4;r++){
        const float v0 = lrelu_f(acc[mi][0][r]);
        const float v1 = lrelu_f(acc[mi][1][r]);
        const int row = wr + mi*16 + lkb*4 + r;
        #pragma unroll
        for (int t=0;t<9;t++){
          float p = v0*w0[t] + v1*w1[t];
          p += __shfl_xor(p,1); p += __shfl_xor(p,2);
          p += __shfl_xor(p,4); p += __shfl_xor(p,8);
          if (l15==0) kp[wcl][row][t] = p;
        }
      }
    __syncthreads();
    for (int i = tid; i < 576; i += 256){
      const int row = i/9, t = i - row*9;
      KP[((size_t)jc*512 + it*64 + row)*9 + t] = kp[0][row][t] + kp[1][row][t];
    }
  } else {
    bid -= 128;
    const int b  = bid>>3;
    const int pt = bid&7;
    const unsigned short* CAa = b ? CA2A : CA1A;   // [64 h][512 c]
    const unsigned short* CAb = b ? CA2B : CA1B;   // [512 c][64 h]
    float* ATT = b ? ATT2 : ATT1;
    f32x4 acc[2][2] = {};
    gemm64(DEGT, CAa, pt*64, 0, 512, tid, lA, lB, acc);

    // HID tile -> LDS, bf16, XOR-swizzled [row p][col h]
    {
      const int wr = (wid>>1)*32, wc = (wid&1)*32;
      #pragma unroll
      for (int mi=0;mi<2;mi++)
        #pragma unroll
        for (int ni=0;ni<2;ni++)
          #pragma unroll
          for (int r=0;r<4;r++){
            const int row = wr + mi*16 + lkb*4 + r;
            const int col = wc + ni*16 + l15;
            hid[row*64 + 8*((col>>3) ^ (row&7)) + (col&7)] = f2bf(lrelu_f(acc[mi][ni][r]));
          }
    }
    __syncthreads();

    const int wr = (wid>>1)*32, wc = (wid&1)*32;
    int boff2[2][2], aoff2[2][2];
    #pragma unroll
    for (int ni=0;ni<2;ni++){
      const int Rb = wc + ni*16 + l15;
      #pragma unroll
      for (int h=0;h<2;h++) boff2[ni][h] = Rb*64 + 8*((h*4 + lkb) ^ (Rb&7));
    }
    #pragma unroll
    for (int mi=0;mi<2;mi++){
      const int Ra = wr + mi*16 + l15;
      #pragma unroll
      for (int h=0;h<2;h++) aoff2[mi][h] = Ra*64 + 8*((h*4 + lkb) ^ (Ra&7));
    }
    bf16x8 bf2[2][2];
    #pragma unroll
    for (int ni=0;ni<2;ni++)
      #pragma unroll
      for (int h=0;h<2;h++) bf2[ni][h] = *(const bf16x8*)(hid + boff2[ni][h]);

    const int arow = tid>>2, akb0 = (tid&3)*2;
    for (int m0=0; m0<512; m0+=64){
      __syncthreads();
      #pragma unroll
      for (int kk=0;kk<2;kk++){
        const int kb = akb0+kk;
        *(ushort8*)(lA + arow*64 + 8*(kb ^ (arow&7))) =
          *(const ushort8*)(CAb + (size_t)(m0+arow)*64 + kb*8);
      }
      __syncthreads();
      f32x4 a2[2][2] = {};
      #pragma unroll
      for (int h=0;h<2;h++)
        #pragma unroll
        for (int mi=0;mi<2;mi++){
          const bf16x8 af2 = *(const bf16x8*)(lA + aoff2[mi][h]);
          #pragma unroll
          for (int ni=0;ni<2;ni++)
            a2[mi][ni] = __builtin_amdgcn_mfma_f32_16x16x32_bf16(af2, bf2[ni][h], a2[mi][ni], 0,0,0);
        }
      #pragma unroll
      for (int mi=0;mi<2;mi++)
        #pragma unroll
        for (int ni=0;ni<2;ni++){
          #pragma unroll
          for (int r=0;r<4;r++){
            const int row = m0 + wr + mi*16 + lkb*4 + r;
            const int col = pt*64 + wc + ni*16 + l15;
            ATT[(size_t)row*512 + col] = 1.f/(1.f + expf(-a2[mi][ni][r]));
          }
        }
    }
  }
}

// ==== depthwise 3x3 (SAME) + lrelu, f32 in, OUT transposed bf16 [px][ch] =====
// kern taps summed from 8 j-chunk partials KP[jc][c][9]
__global__ __launch_bounds__(512) void k_dwconv(const float* __restrict__ x,
    const float* __restrict__ KP, unsigned short* __restrict__ yt){
  const int c = blockIdx.x;
  const int p = threadIdx.x;
  const int iy = p>>5, ix = p&31;
  __shared__ float plane[18*34];
  __shared__ float ks[9];
  for (int i=p;i<18*34;i+=512) plane[i]=0.f;
  if (p < 9){
    float s = 0.f;
    #pragma unroll
    for (int jc=0;jc<8;jc++) s += KP[((size_t)jc*512 + c)*9 + p];
    ks[p] = s;
  }
  __syncthreads();
  plane[(iy+1)*34 + ix+1] = x[c*512 + p];
  __syncthreads();
  float s = 0.f;
  #pragma unroll
  for (int dy=0;dy<3;dy++)
    #pragma unroll
    for (int dx=0;dx<3;dx++)
      s += plane[(iy+dy)*34 + ix+dx]*ks[dy*3+dx];
  yt[(size_t)p*512 + c] = f2bf(lrelu_f(s));
}

// ==== fused: reduce bf16 conv partials + bias + lrelu, then dw -> yt =========
__global__ __launch_bounds__(512) void k_dwconv_red(const unsigned short* __restrict__ part,
    const float* __restrict__ bias, const float* __restrict__ KP,
    unsigned short* __restrict__ yt, int nchunks){
  const int c = blockIdx.x;
  const int p = threadIdx.x;
  const int iy = p>>5, ix = p&31;
  __shared__ float plane[18*34];
  __shared__ float ks[9];
  for (int i=p;i<18*34;i+=512) plane[i]=0.f;
  if (p < 9){
    float s = 0.f;
    #pragma unroll
    for (int jc=0;jc<8;jc++) s += KP[((size_t)jc*512 + c)*9 + p];
    ks[p] = s;
  }
  __syncthreads();
  if (p < 128){
    const float b = bias[c];
    float4 a4 = {b,b,b,b};
    for (int s=0;s<nchunks;s++){
      const ushort4v v = ((const ushort4v*)(part + (size_t)s*262144 + c*512))[p];
      a4.x += bf2f(v.x); a4.y += bf2f(v.y); a4.z += bf2f(v.z); a4.w += bf2f(v.w);
    }
    a4.x = lrelu_f(a4.x); a4.y = lrelu_f(a4.y);
    a4.z = lrelu_f(a4.z); a4.w = lrelu_f(a4.w);
    const int px0 = p*4;
    float* dst = &plane[((px0>>5)+1)*34 + (px0&31)+1];
    dst[0]=a4.x; dst[1]=a4.y; dst[2]=a4.z; dst[3]=a4.w;
  }
  __syncthreads();
  float s = 0.f;
  #pragma unroll
  for (int dy=0;dy<3;dy++)
    #pragma unroll
    for (int dx=0;dx<3;dx++)
      s += plane[(iy+dy)*34 + ix+dx]*ks[dy*3+dx];
  yt[(size_t)p*512 + c] = f2bf(lrelu_f(s));
}

// ==== pointwise GEMM 32x32-tile, dbuf single-barrier ====
__global__ __launch_bounds__(256) void k_pw(
    const unsigned short* __restrict__ A, const unsigned short* __restrict__ Bt,
    const float* __restrict__ bias,
    const float* __restrict__ E1, const float* __restrict__ E2,
    unsigned short* __restrict__ XT){
  __shared__ unsigned short lA[2][1024], lB[2][1024];
  __shared__ float tile[32][33];
  const int tid = threadIdx.x;
  const int wid = tid>>6, lane = tid&63;
  const int M0 = blockIdx.x*32, N0 = blockIdx.y*32;

  const int half = tid>>7;
  const int st_ = tid&127;
  const int srow = st_>>2, skb = st_&3;
  const unsigned short* gS = (half ? Bt + (size_t)(N0+srow)*512
                                   : A  + (size_t)(M0+srow)*512) + skb*8;
  unsigned short (*lS)[1024] = half ? lB : lA;
  const int soff = srow*32 + 8*(skb ^ (srow&3));

  const int wr = (wid>>1)*16, wc = (wid&1)*16;
  const int l15 = lane&15, lkb = lane>>4;
  const int Ra = wr + l15, Rb = wc + l15;
  const int aoff = Ra*32 + 8*(lkb ^ (Ra&3));
  const int boff = Rb*32 + 8*(lkb ^ (Rb&3));

  f32x4 acc = {};
  ushort8 r0 = *(const ushort8*)gS;
  *(ushort8*)(&lS[0][soff]) = r0;
  r0 = *(const ushort8*)(gS+32);
  __syncthreads();
  for (int st=0; st<16; ++st){
    const int cur = st&1;
    const bf16x8 af = *(const bf16x8*)(&lA[cur][aoff]);
    const bf16x8 bf = *(const bf16x8*)(&lB[cur][boff]);
    if (st+1 < 16){
      *(ushort8*)(&lS[cur^1][soff]) = r0;
      if (st+2 < 16) r0 = *(const ushort8*)(gS + (size_t)(st+2)*32);
    }
    acc = __builtin_amdgcn_mfma_f32_16x16x32_bf16(af, bf, acc, 0,0,0);
    __syncthreads();
  }

  #pragma unroll
  for (int r=0;r<4;r++){
    const int rl = wr + lkb*4 + r;
    const int cl = wc + l15;
    const int rr = M0 + rl, col = N0 + cl;
    float v = acc[r] + bias[rr] + E1[(size_t)rr*512+col]*E2[(size_t)rr*512+col];
    tile[rl][cl] = lrelu_f(v);
  }
  __syncthreads();
  const int pr = tid>>3, q = tid&7;
  ushort4v o;
  o.x = f2bf(tile[q*4+0][pr]); o.y = f2bf(tile[q*4+1][pr]);
  o.z = f2bf(tile[q*4+2][pr]); o.w = f2bf(tile[q*4+3][pr]);
  *(ushort4v*)(XT + (size_t)(N0+pr)*512 + M0 + q*4) = o;
}

// ===== conv 3x3 MFMA GEMM 64x128 tile, BK=64 steps, bf16 partials ============
template<int KCH>   // 256
__global__ __launch_bounds__(256) void k_mfma_conv(
    const unsigned short* __restrict__ WB,
    const unsigned short* __restrict__ XT,
    unsigned short* __restrict__ part){
  __shared__ unsigned short lA[2][4096];
  __shared__ unsigned short lB[2][8192];
  const int tid = threadIdx.x;
  const int wid = tid>>6, lane = tid&63;
  const int m0 = blockIdx.x*64, n0 = blockIdx.y*128;
  const int k0 = blockIdx.z*KCH;

  const int srow = tid>>2, skb = tid&3;
  const unsigned short* gA = WB + (size_t)(m0+srow)*4608 + k0 + skb*8;
  const int brow1 = srow + 64;
  const int p0 = n0 + srow, p1 = n0 + brow1;
  const int py0 = p0>>5, px0 = p0&31, py1 = p1>>5, px1 = p1&31;
  const int s7 = srow&7;
  const int soffA0 = srow*64 + 8*(skb ^ s7);
  const int soffA1 = srow*64 + 8*((skb+4) ^ s7);
  const int soffB00 = soffA0,            soffB01 = soffA1;
  const int soffB10 = brow1*64 + 8*(skb ^ s7);
  const int soffB11 = brow1*64 + 8*((skb+4) ^ s7);

  const int wr = (wid>>1)*32, wc = (wid&1)*64;
  const int l15 = lane&15, lkb = lane>>4;
  int aoff[2][2], boff[4][2];
  #pragma unroll
  for (int s=0;s<2;s++){
    const int Ra = wr + s*16 + l15;
    #pragma unroll
    for (int h=0;h<2;h++) aoff[s][h] = Ra*64 + 8*((lkb+4*h) ^ (Ra&7));
  }
  #pragma unroll
  for (int u=0;u<4;u++){
    const int Rb = wc + u*16 + l15;
    #pragma unroll
    for (int h=0;h<2;h++) boff[u][h] = Rb*64 + 8*((lkb+4*h) ^ (Rb&7));
  }

  auto ldB = [&](int st, int py, int px, ushort8& lo, ushort8& hi){
    const int k = k0 + st*64;
    const int t = k>>9;
    const int dy = t/3, dx = t - dy*3;
    const int yy = py + dy - 1, xx = px + dx - 1;
    lo = (ushort8){}; hi = (ushort8){};
    if ((unsigned)yy < 16u && (unsigned)xx < 32u){
      const unsigned short* b = XT + (size_t)(yy*32+xx)*512 + (k&511) + skb*8;
      lo = *(const ushort8*)b; hi = *(const ushort8*)(b+32);
    }
  };

  constexpr int NST = KCH/64;
  f32x4 acc[2][4] = {};
  ushort8 ra0 = *(const ushort8*)gA;
  ushort8 ra1 = *(const ushort8*)(gA+32);
  ushort8 b00,b01,b10,b11;
  ldB(0, py0, px0, b00, b01);
  ldB(0, py1, px1, b10, b11);
  *(ushort8*)(&lA[0][soffA0]) = ra0;  *(ushort8*)(&lA[0][soffA1]) = ra1;
  *(ushort8*)(&lB[0][soffB00]) = b00; *(ushort8*)(&lB[0][soffB01]) = b01;
  *(ushort8*)(&lB[0][soffB10]) = b10; *(ushort8*)(&lB[0][soffB11]) = b11;
  if (NST > 1){
    ra0 = *(const ushort8*)(gA+64); ra1 = *(const ushort8*)(gA+96);
    ldB(1, py0, px0, b00, b01);
    ldB(1, py1, px1, b10, b11);
  }
  __syncthreads();
  for (int st=0; st<NST; ++st){
    const int cur = st&1;
    bf16x8 af[2][2], bfr[4][2];
    #pragma unroll
    for (int s=0;s<2;s++)
      #pragma unroll
      for (int h=0;h<2;h++) af[s][h] = *(const bf16x8*)(&lA[cur][aoff[s][h]]);
    #pragma unroll
    for (int u=0;u<4;u++)
      #pragma unroll
      for (int h=0;h<2;h++) bfr[u][h] = *(const bf16x8*)(&lB[cur][boff[u][h]]);
    if (st+1 < NST){
      const int nxt = cur^1;
      *(ushort8*)(&lA[nxt][soffA0]) = ra0;  *(ushort8*)(&lA[nxt][soffA1]) = ra1;
      *(ushort8*)(&lB[nxt][soffB00]) = b00; *(ushort8*)(&lB[nxt][soffB01]) = b01;
      *(ushort8*)(&lB[nxt][soffB10]) = b10; *(ushort8*)(&lB[nxt][soffB11]) = b11;
      if (st+2 < NST){
        ra0 = *(const ushort8*)(gA + (size_t)(st+2)*64);
        ra1 = *(const ushort8*)(gA + (size_t)(st+2)*64 + 32);
        ldB(st+2, py0, px0, b00, b01);
        ldB(st+2, py1, px1, b10, b11);
      }
    }
    #pragma unroll
    for (int h=0;h<2;h++)
      #pragma unroll
      for (int s=0;s<2;s++)
        #pragma unroll
        for (int u=0;u<4;u++)
          acc[s][u] = __builtin_amdgcn_mfma_f32_16x16x32_bf16(af[s][h], bfr[u][h], acc[s][u], 0,0,0);
    __syncthreads();
  }

  unsigned short* pbase = part + (size_t)blockIdx.z*262144;
  #pragma unroll
  for (int s=0;s<2;s++)
    #pragma unroll
    for (int u=0;u<4;u++){
      const int row = m0 + wr + s*16 + lkb*4;
      const int col = n0 + wc + u*16 + l15;
      #pragma unroll
      for (int r=0;r<4;r++)
        pbase[(size_t)(row+r)*512 + col] = f2bf(acc[s][u][r]);
    }
}

// ===== final reduce: bias + bf16 partials + residual =========================
__global__ __launch_bounds__(256) void k_reduce_final(const unsigned short* __restrict__ part,
    const float* __restrict__ bias, const float* __restrict__ res,
    float* __restrict__ y, int nchunks){
  const int i = blockIdx.x*256 + threadIdx.x;
  const int o = i>>7;
  const float b = bias[o];
  float4 a4 = {b,b,b,b};
  for (int s=0;s<nchunks;s++){
    const ushort4v v = ((const ushort4v*)part)[(size_t)s*65536 + i];
    a4.x += bf2f(v.x); a4.y += bf2f(v.y); a4.z += bf2f(v.z); a4.w += bf2f(v.w);
  }
  const float4 rv = ((const float4*)res)[i];
  a4.x += rv.x; a4.y += rv.y; a4.z += rv.z; a4.w += rv.w;
  ((float4*)y)[i] = a4;
}

extern "C" void kernel_launch(void* const* d_in, const int* in_sizes, int n_in,
                              void* d_out, int out_size, void* d_ws, size_t ws_size,
                              hipStream_t stream) {
  (void)in_sizes; (void)n_in; (void)out_size; (void)ws_size;
  const float* xin    = (const float*)d_in[0];
  const float* deg    = (const float*)d_in[1];
  const float* k1_w1  = (const float*)d_in[2];
  const float* k1_w2  = (const float*)d_in[3];
  const float* p1_w   = (const float*)d_in[4];
  const float* p1_b   = (const float*)d_in[5];
  const float* ca1_w1 = (const float*)d_in[6];
  const float* ca1_w2 = (const float*)d_in[7];
  const float* conv1_w= (const float*)d_in[8];
  const float* conv1_b= (const float*)d_in[9];
  const float* k2_w1  = (const float*)d_in[10];
  const float* k2_w2  = (const float*)d_in[11];
  const float* p2_w   = (const float*)d_in[12];
  const float* p2_b   = (const float*)d_in[13];
  const float* ca2_w1 = (const float*)d_in[14];
  const float* ca2_w2 = (const float*)d_in[15];
  const float* conv2_w= (const float*)d_in[16];
  const float* conv2_b= (const float*)d_in[17];
  float* out = (float*)d_out;

  const int NS = 18;                       // conv split-K chunks (KCH=256)

  // ---- workspace ----
  float* ws = (float*)d_ws;
  unsigned short* PART = (unsigned short*)ws;
  ws += (size_t)NS*131072;                 // 9.4 MB
  float* KP1  = ws;  ws += 36864;          // 8 jc x 512 c x 9 t
  float* KP2  = ws;  ws += 36864;
  float* ATT1 = ws;  ws += 262144;
  float* ATT2 = ws;  ws += 262144;
  unsigned short* DEGB = (unsigned short*)ws; ws += 131072;
  unsigned short* DEGT = (unsigned short*)ws; ws += 131072;
  unsigned short* K1B  = (unsigned short*)ws; ws += 131072;
  unsigned short* K2B  = (unsigned short*)ws; ws += 131072;
  unsigned short* P1B  = (unsigned short*)ws; ws += 131072;
  unsigned short* P2B  = (unsigned short*)ws; ws += 131072;
  unsigned short* CA1A = (unsigned short*)ws; ws += 16384;
  unsigned short* CA1B = (unsigned short*)ws; ws += 16384;
  unsigned short* CA2A = (unsigned short*)ws; ws += 16384;
  unsigned short* CA2B = (unsigned short*)ws; ws += 16384;
  unsigned short* DWLT = (unsigned short*)ws; ws += 131072;
  unsigned short* XT   = (unsigned short*)ws; ws += 131072;
  unsigned short* WB1  = (unsigned short*)ws; ws += 1179648;
  unsigned short* WB2  = (unsigned short*)ws; ws += 1179648;

  // 1. all weight packs
  k_pack_all<<<6272,256,0,stream>>>(k1_w1,k2_w1,p1_w,p2_w,
      ca1_w1,ca1_w2,ca2_w1,ca2_w2, deg, conv1_w, conv2_w,
      K1B,K2B,P1B,P2B, CA1A,CA1B,CA2A,CA2B, DEGB,DEGT, WB1,WB2);

  // 2. fused pre-phase: kern partials + attention maps
  k_prep<<<144,256,0,stream>>>(DEGB,DEGT, K1B,K2B, CA1A,CA2A, CA1B,CA2B,
      k1_w2,k2_w2, KP1,KP2, ATT1,ATT2);

  // 3. da_conv1 depthwise -> DWLT [px][ch] bf16
  k_dwconv<<<512,512,0,stream>>>(xin, KP1, DWLT);
  // 4. pointwise 1 (+bias+deg*att+lrelu) -> XT
  k_pw<<<dim3(16,16),256,0,stream>>>(P1B, DWLT, p1_b, deg, ATT1, XT);
  // 5. conv1 3x3 (64x128 tile, BK=64, split-K=18)
  k_mfma_conv<256><<<dim3(8,4,18),256,0,stream>>>(WB1, XT, PART);
  // 6. fused reduce+lrelu+depthwise (da_conv2) -> DWLT
  k_dwconv_red<<<512,512,0,stream>>>(PART, conv1_b, KP2, DWLT, NS);
  // 7. pointwise 2 -> XT
  k_pw<<<dim3(16,16),256,0,stream>>>(P2B, DWLT, p2_b, deg, ATT2, XT);
  // 8. conv2 3x3
  k_mfma_conv<256><<<dim3(8,4,18),256,0,stream>>>(WB2, XT, PART);
  // 9. final reduce + bias + residual
  k_reduce_final<<<256,256,0,stream>>>(PART, conv2_b, xin, out, NS);
}

// Round 10
// 87.798 us; speedup vs baseline: 1.0085x; 1.0085x over previous
//
#include <hip/hip_runtime.h>
#include <hip/hip_bf16.h>

typedef __attribute__((ext_vector_type(8))) unsigned short ushort8;
typedef __attribute__((ext_vector_type(8))) __bf16 bf16x8;
typedef __attribute__((ext_vector_type(4))) float f32x4;
typedef __attribute__((ext_vector_type(4))) unsigned short ushort4v;

__device__ __forceinline__ float lrelu_f(float v){ return v > 0.f ? v : 0.1f*v; }

__device__ __forceinline__ unsigned short f2bf(float v){
  unsigned u = __float_as_uint(v);
  unsigned r = (u + 0x7fffu + ((u>>16)&1u)) >> 16;
  return (unsigned short)r;
}
__device__ __forceinline__ float bf2f(unsigned short u){
  return __uint_as_float(((unsigned)u)<<16);
}

__device__ __forceinline__ void packq(const float* __restrict__ s,
                                      unsigned short* __restrict__ d, int i){
  const float4 v = ((const float4*)s)[i];
  ushort4v o; o.x=f2bf(v.x); o.y=f2bf(v.y); o.z=f2bf(v.z); o.w=f2bf(v.w);
  *(ushort4v*)(d + (size_t)i*4) = o;
}

// ============ one fused pack kernel: all weights -> bf16 ============
__global__ __launch_bounds__(256) void k_pack_all(
  const float* __restrict__ k1_w1, const float* __restrict__ k2_w1,
  const float* __restrict__ p1_w,  const float* __restrict__ p2_w,
  const float* __restrict__ ca1_w1,const float* __restrict__ ca1_w2,
  const float* __restrict__ ca2_w1,const float* __restrict__ ca2_w2,
  const float* __restrict__ deg,   const float* __restrict__ conv1_w,
  const float* __restrict__ conv2_w,
  unsigned short* __restrict__ K1B, unsigned short* __restrict__ K2B,
  unsigned short* __restrict__ P1B, unsigned short* __restrict__ P2B,
  unsigned short* __restrict__ CA1A,unsigned short* __restrict__ CA1B,
  unsigned short* __restrict__ CA2A,unsigned short* __restrict__ CA2B,
  unsigned short* __restrict__ DEGB,unsigned short* __restrict__ DEGT,
  unsigned short* __restrict__ WB1, unsigned short* __restrict__ WB2){
  int i = blockIdx.x*256 + threadIdx.x;
  if (i < 65536){ packq(k1_w1, K1B, i); return; } i -= 65536;
  if (i < 65536){ packq(k2_w1, K2B, i); return; } i -= 65536;
  if (i < 65536){ packq(p1_w,  P1B, i); return; } i -= 65536;
  if (i < 65536){ packq(p2_w,  P2B, i); return; } i -= 65536;
  if (i < 8192){ packq(ca1_w1, CA1A, i); return; } i -= 8192;
  if (i < 8192){ packq(ca1_w2, CA1B, i); return; } i -= 8192;
  if (i < 8192){ packq(ca2_w1, CA2A, i); return; } i -= 8192;
  if (i < 8192){ packq(ca2_w2, CA2B, i); return; } i -= 8192;
  if (i < 65536){ packq(deg, DEGB, i); return; } i -= 65536;
  if (i < 65536){                      // DEGT: bf16 transpose of deg
    const int j = i*4; const int p = j>>9, c = j&511;
    ushort4v o;
    o.x = f2bf(deg[(size_t)(c+0)*512 + p]);
    o.y = f2bf(deg[(size_t)(c+1)*512 + p]);
    o.z = f2bf(deg[(size_t)(c+2)*512 + p]);
    o.w = f2bf(deg[(size_t)(c+3)*512 + p]);
    *(ushort4v*)(DEGT + (size_t)j) = o;
    return;
  } i -= 65536;
  if (i < 589824){                     // WB1: [o][t*512+ci] = w[o][ci*9+t]
    const int o_ = i/1152; const int r4 = (i - o_*1152)*4;
    const int t = r4>>9; const int ci = r4&511;
    const float* s = conv1_w + (size_t)o_*4608;
    ushort4v o;
    o.x = f2bf(s[(ci+0)*9 + t]); o.y = f2bf(s[(ci+1)*9 + t]);
    o.z = f2bf(s[(ci+2)*9 + t]); o.w = f2bf(s[(ci+3)*9 + t]);
    *(ushort4v*)(WB1 + (size_t)o_*4608 + r4) = o;
    return;
  } i -= 589824;
  if (i < 589824){                     // WB2
    const int o_ = i/1152; const int r4 = (i - o_*1152)*4;
    const int t = r4>>9; const int ci = r4&511;
    const float* s = conv2_w + (size_t)o_*4608;
    ushort4v o;
    o.x = f2bf(s[(ci+0)*9 + t]); o.y = f2bf(s[(ci+1)*9 + t]);
    o.z = f2bf(s[(ci+2)*9 + t]); o.w = f2bf(s[(ci+3)*9 + t]);
    *(ushort4v*)(WB2 + (size_t)o_*4608 + r4) = o;
  }
}

// ======= shared 64x64 MFMA GEMM core, 4 waves, dbuf single-barrier =======
__device__ __forceinline__ void gemm64(
    const unsigned short* __restrict__ A, const unsigned short* __restrict__ Bt,
    int m0, int n0, int K, int tid,
    unsigned short* lA, unsigned short* lB, f32x4 acc[2][2]){
  const int wid = tid>>6, lane = tid&63;
  const int srow = tid>>2, skb = tid&3;
  const unsigned short* gA = A  + (size_t)(m0+srow)*K + skb*8;
  const unsigned short* gB = Bt + (size_t)(n0+srow)*K + skb*8;
  const int soff = srow*32 + 8*(skb ^ (srow&3));
  const int wr = (wid>>1)*32, wc = (wid&1)*32;
  const int l15 = lane&15, lkb = lane>>4;
  int aoff[2], boff[2];
  #pragma unroll
  for (int s=0;s<2;s++){
    const int Ra = wr + s*16 + l15;
    aoff[s] = Ra*32 + 8*(lkb ^ (Ra&3));
    const int Rb = wc + s*16 + l15;
    boff[s] = Rb*32 + 8*(lkb ^ (Rb&3));
  }
  const int nst = K>>5;
  ushort8 ra = *(const ushort8*)gA;
  ushort8 rb = *(const ushort8*)gB;
  *(ushort8*)(lA + soff) = ra;
  *(ushort8*)(lB + soff) = rb;
  if (nst > 1){ ra = *(const ushort8*)(gA+32); rb = *(const ushort8*)(gB+32); }
  __syncthreads();
  for (int st=0; st<nst; ++st){
    const int cur = (st&1)*2048;
    bf16x8 af[2], bfr[2];
    #pragma unroll
    for (int s=0;s<2;s++){
      af[s]  = *(const bf16x8*)(lA + cur + aoff[s]);
      bfr[s] = *(const bf16x8*)(lB + cur + boff[s]);
    }
    if (st+1 < nst){
      const int nxt = ((st+1)&1)*2048;
      *(ushort8*)(lA + nxt + soff) = ra;
      *(ushort8*)(lB + nxt + soff) = rb;
      if (st+2 < nst){
        ra = *(const ushort8*)(gA + (size_t)(st+2)*32);
        rb = *(const ushort8*)(gB + (size_t)(st+2)*32);
      }
    }
    #pragma unroll
    for (int mi=0;mi<2;mi++)
      #pragma unroll
      for (int ni=0;ni<2;ni++)
        acc[mi][ni] = __builtin_amdgcn_mfma_f32_16x16x32_bf16(af[mi], bfr[ni], acc[mi][ni], 0,0,0);
    __syncthreads();
  }
}

// ======= fused pre-phase, 256 uniform blocks =======
// blocks 0..127: kern branch (b = bid>>6, i-tile = (bid&63)>>3, j-chunk = bid&7)
//   64x64x512 GEMM (deg @ kw1^T) + in-register kw2 contraction -> KP partials
// blocks 128..255: att branch (b, m-tile, p-tile): recompute HID p-tile
//   (64x64x512 GEMM), then 64x64x64 GEMM + sigmoid -> ATT tile.
__global__ __launch_bounds__(256) void k_prep(
    const unsigned short* __restrict__ DEGB, const unsigned short* __restrict__ DEGT,
    const unsigned short* __restrict__ K1B,  const unsigned short* __restrict__ K2B,
    const unsigned short* __restrict__ CA1A, const unsigned short* __restrict__ CA2A,
    const unsigned short* __restrict__ CA1B, const unsigned short* __restrict__ CA2B,
    const float* __restrict__ kw2a, const float* __restrict__ kw2b,
    float* __restrict__ KP1, float* __restrict__ KP2,
    float* __restrict__ ATT1, float* __restrict__ ATT2){
  __shared__ unsigned short lA[4096], lB[4096];
  __shared__ float kp[2][64][9];
  __shared__ unsigned short hid[4096];
  int bid = blockIdx.x;
  const int tid = threadIdx.x;
  const int wid = tid>>6, lane = tid&63;
  const int l15 = lane&15, lkb = lane>>4;

  if (bid < 128){
    const int b  = bid>>6;
    const int r6 = bid&63;
    const int it = r6>>3, jc = r6&7;
    const unsigned short* Bt = b ? K2B : K1B;
    const float* kw2 = b ? kw2b : kw2a;
    float* KP = b ? KP2 : KP1;
    f32x4 acc[2][2] = {};
    gemm64(DEGB, Bt, it*64, jc*64, 512, tid, lA, lB, acc);

    const int wr = (wid>>1)*32, wcl = wid&1;
    const int col0 = wcl*32 + l15, col1 = col0 + 16;
    float w0[9], w1[9];
    #pragma unroll
    for (int t=0;t<9;t++){
      w0[t] = kw2[t*512 + jc*64 + col0];
      w1[t] = kw2[t*512 + jc*64 + col1];
    }
    #pragma unroll
    for (int mi=0;mi<2;mi++)
      #pragma unroll
      for (int r=0;r<4;r++){
        const float v0 = lrelu_f(acc[mi][0][r]);
        const float v1 = lrelu_f(acc[mi][1][r]);
        const int row = wr + mi*16 + lkb*4 + r;
        #pragma unroll
        for (int t=0;t<9;t++){
          float p = v0*w0[t] + v1*w1[t];
          p += __shfl_xor(p,1); p += __shfl_xor(p,2);
          p += __shfl_xor(p,4); p += __shfl_xor(p,8);
          if (l15==0) kp[wcl][row][t] = p;
        }
      }
    __syncthreads();
    for (int i = tid; i < 576; i += 256){
      const int row = i/9, t = i - row*9;
      KP[((size_t)jc*512 + it*64 + row)*9 + t] = kp[0][row][t] + kp[1][row][t];
    }
  } else {
    bid -= 128;
    const int b  = bid>>6;
    const int r6 = bid&63;
    const int mt = r6>>3, pt = r6&7;
    const unsigned short* CAa = b ? CA2A : CA1A;   // [64 h][512 c]
    const unsigned short* CAb = b ? CA2B : CA1B;   // [512 c][64 h]
    float* ATT = b ? ATT2 : ATT1;
    // HID p-tile: [64 px][64 h] = lrelu(DEGT[pt*64..][512] @ CAa^T)
    f32x4 acc[2][2] = {};
    gemm64(DEGT, CAa, pt*64, 0, 512, tid, lA, lB, acc);

    const int wr = (wid>>1)*32, wc = (wid&1)*32;
    #pragma unroll
    for (int mi=0;mi<2;mi++)
      #pragma unroll
      for (int ni=0;ni<2;ni++)
        #pragma unroll
        for (int r=0;r<4;r++){
          const int row = wr + mi*16 + lkb*4 + r;    // px
          const int col = wc + ni*16 + l15;          // h
          hid[row*64 + 8*((col>>3) ^ (row&7)) + (col&7)] = f2bf(lrelu_f(acc[mi][ni][r]));
        }
    __syncthreads();
    // load ca_w2 m-tile [64 c][64 h] into lA (swizzled 64-k rows)
    const int arow = tid>>2, akb0 = (tid&3)*2;
    #pragma unroll
    for (int kk=0;kk<2;kk++){
      const int kb = akb0+kk;
      *(ushort8*)(lA + arow*64 + 8*(kb ^ (arow&7))) =
        *(const ushort8*)(CAb + (size_t)(mt*64+arow)*64 + kb*8);
    }
    __syncthreads();
    // ATT tile [64 c][64 px] = sigmoid(ca_w2_tile @ HID^T)
    f32x4 a2[2][2] = {};
    #pragma unroll
    for (int h=0;h<2;h++){
      bf16x8 af2[2], bf2[2];
      #pragma unroll
      for (int mi=0;mi<2;mi++){
        const int Ra = wr + mi*16 + l15;
        af2[mi] = *(const bf16x8*)(lA + Ra*64 + 8*((h*4+lkb) ^ (Ra&7)));
      }
      #pragma unroll
      for (int ni=0;ni<2;ni++){
        const int Rb = wc + ni*16 + l15;
        bf2[ni] = *(const bf16x8*)(hid + Rb*64 + 8*((h*4+lkb) ^ (Rb&7)));
      }
      #pragma unroll
      for (int mi=0;mi<2;mi++)
        #pragma unroll
        for (int ni=0;ni<2;ni++)
          a2[mi][ni] = __builtin_amdgcn_mfma_f32_16x16x32_bf16(af2[mi], bf2[ni], a2[mi][ni], 0,0,0);
    }
    #pragma unroll
    for (int mi=0;mi<2;mi++)
      #pragma unroll
      for (int ni=0;ni<2;ni++)
        #pragma unroll
        for (int r=0;r<4;r++){
          const int row = mt*64 + wr + mi*16 + lkb*4 + r;
          const int col = pt*64 + wc + ni*16 + l15;
          ATT[(size_t)row*512 + col] = 1.f/(1.f + expf(-a2[mi][ni][r]));
        }
  }
}

// ==== depthwise 3x3 (SAME) + lrelu, f32 in, OUT transposed bf16 [px][ch] =====
__global__ __launch_bounds__(512) void k_dwconv(const float* __restrict__ x,
    const float* __restrict__ KP, unsigned short* __restrict__ yt){
  const int c = blockIdx.x;
  const int p = threadIdx.x;
  const int iy = p>>5, ix = p&31;
  __shared__ float plane[18*34];
  __shared__ float ks[9];
  for (int i=p;i<18*34;i+=512) plane[i]=0.f;
  if (p < 9){
    float s = 0.f;
    #pragma unroll
    for (int jc=0;jc<8;jc++) s += KP[((size_t)jc*512 + c)*9 + p];
    ks[p] = s;
  }
  __syncthreads();
  plane[(iy+1)*34 + ix+1] = x[c*512 + p];
  __syncthreads();
  float s = 0.f;
  #pragma unroll
  for (int dy=0;dy<3;dy++)
    #pragma unroll
    for (int dx=0;dx<3;dx++)
      s += plane[(iy+dy)*34 + ix+dx]*ks[dy*3+dx];
  yt[(size_t)p*512 + c] = f2bf(lrelu_f(s));
}

// ==== fused: reduce bf16 conv partials + bias + lrelu, then dw -> yt =========
__global__ __launch_bounds__(512) void k_dwconv_red(const unsigned short* __restrict__ part,
    const float* __restrict__ bias, const float* __restrict__ KP,
    unsigned short* __restrict__ yt, int nchunks){
  const int c = blockIdx.x;
  const int p = threadIdx.x;
  const int iy = p>>5, ix = p&31;
  __shared__ float plane[18*34];
  __shared__ float ks[9];
  for (int i=p;i<18*34;i+=512) plane[i]=0.f;
  if (p < 9){
    float s = 0.f;
    #pragma unroll
    for (int jc=0;jc<8;jc++) s += KP[((size_t)jc*512 + c)*9 + p];
    ks[p] = s;
  }
  __syncthreads();
  if (p < 128){
    const float b = bias[c];
    float4 a4 = {b,b,b,b};
    for (int s=0;s<nchunks;s++){
      const ushort4v v = ((const ushort4v*)(part + (size_t)s*262144 + c*512))[p];
      a4.x += bf2f(v.x); a4.y += bf2f(v.y); a4.z += bf2f(v.z); a4.w += bf2f(v.w);
    }
    a4.x = lrelu_f(a4.x); a4.y = lrelu_f(a4.y);
    a4.z = lrelu_f(a4.z); a4.w = lrelu_f(a4.w);
    const int px0 = p*4;
    float* dst = &plane[((px0>>5)+1)*34 + (px0&31)+1];
    dst[0]=a4.x; dst[1]=a4.y; dst[2]=a4.z; dst[3]=a4.w;
  }
  __syncthreads();
  float s = 0.f;
  #pragma unroll
  for (int dy=0;dy<3;dy++)
    #pragma unroll
    for (int dx=0;dx<3;dx++)
      s += plane[(iy+dy)*34 + ix+dx]*ks[dy*3+dx];
  yt[(size_t)p*512 + c] = f2bf(lrelu_f(s));
}

// ==== pointwise GEMM 32x32-tile, dbuf single-barrier ====
__global__ __launch_bounds__(256) void k_pw(
    const unsigned short* __restrict__ A, const unsigned short* __restrict__ Bt,
    const float* __restrict__ bias,
    const float* __restrict__ E1, const float* __restrict__ E2,
    unsigned short* __restrict__ XT){
  __shared__ unsigned short lA[2][1024], lB[2][1024];
  __shared__ float tile[32][33];
  const int tid = threadIdx.x;
  const int wid = tid>>6, lane = tid&63;
  const int M0 = blockIdx.x*32, N0 = blockIdx.y*32;

  const int half = tid>>7;
  const int st_ = tid&127;
  const int srow = st_>>2, skb = st_&3;
  const unsigned short* gS = (half ? Bt + (size_t)(N0+srow)*512
                                   : A  + (size_t)(M0+srow)*512) + skb*8;
  unsigned short (*lS)[1024] = half ? lB : lA;
  const int soff = srow*32 + 8*(skb ^ (srow&3));

  const int wr = (wid>>1)*16, wc = (wid&1)*16;
  const int l15 = lane&15, lkb = lane>>4;
  const int Ra = wr + l15, Rb = wc + l15;
  const int aoff = Ra*32 + 8*(lkb ^ (Ra&3));
  const int boff = Rb*32 + 8*(lkb ^ (Rb&3));

  f32x4 acc = {};
  ushort8 r0 = *(const ushort8*)gS;
  *(ushort8*)(&lS[0][soff]) = r0;
  r0 = *(const ushort8*)(gS+32);
  __syncthreads();
  for (int st=0; st<16; ++st){
    const int cur = st&1;
    const bf16x8 af = *(const bf16x8*)(&lA[cur][aoff]);
    const bf16x8 bf = *(const bf16x8*)(&lB[cur][boff]);
    if (st+1 < 16){
      *(ushort8*)(&lS[cur^1][soff]) = r0;
      if (st+2 < 16) r0 = *(const ushort8*)(gS + (size_t)(st+2)*32);
    }
    acc = __builtin_amdgcn_mfma_f32_16x16x32_bf16(af, bf, acc, 0,0,0);
    __syncthreads();
  }

  #pragma unroll
  for (int r=0;r<4;r++){
    const int rl = wr + lkb*4 + r;
    const int cl = wc + l15;
    const int rr = M0 + rl, col = N0 + cl;
    float v = acc[r] + bias[rr] + E1[(size_t)rr*512+col]*E2[(size_t)rr*512+col];
    tile[rl][cl] = lrelu_f(v);
  }
  __syncthreads();
  const int pr = tid>>3, q = tid&7;
  ushort4v o;
  o.x = f2bf(tile[q*4+0][pr]); o.y = f2bf(tile[q*4+1][pr]);
  o.z = f2bf(tile[q*4+2][pr]); o.w = f2bf(tile[q*4+3][pr]);
  *(ushort4v*)(XT + (size_t)(N0+pr)*512 + M0 + q*4) = o;
}

// ===== conv 3x3 MFMA GEMM 64x128 tile, BK=64 steps, bf16 partials ============
template<int KCH>   // 256
__global__ __launch_bounds__(256) void k_mfma_conv(
    const unsigned short* __restrict__ WB,
    const unsigned short* __restrict__ XT,
    unsigned short* __restrict__ part){
  __shared__ unsigned short lA[2][4096];
  __shared__ unsigned short lB[2][8192];
  const int tid = threadIdx.x;
  const int wid = tid>>6, lane = tid&63;
  const int m0 = blockIdx.x*64, n0 = blockIdx.y*128;
  const int k0 = blockIdx.z*KCH;

  const int srow = tid>>2, skb = tid&3;
  const unsigned short* gA = WB + (size_t)(m0+srow)*4608 + k0 + skb*8;
  const int brow1 = srow + 64;
  const int p0 = n0 + srow, p1 = n0 + brow1;
  const int py0 = p0>>5, px0 = p0&31, py1 = p1>>5, px1 = p1&31;
  const int s7 = srow&7;
  const int soffA0 = srow*64 + 8*(skb ^ s7);
  const int soffA1 = srow*64 + 8*((skb+4) ^ s7);
  const int soffB00 = soffA0,            soffB01 = soffA1;
  const int soffB10 = brow1*64 + 8*(skb ^ s7);
  const int soffB11 = brow1*64 + 8*((skb+4) ^ s7);

  const int wr = (wid>>1)*32, wc = (wid&1)*64;
  const int l15 = lane&15, lkb = lane>>4;
  int aoff[2][2], boff[4][2];
  #pragma unroll
  for (int s=0;s<2;s++){
    const int Ra = wr + s*16 + l15;
    #pragma unroll
    for (int h=0;h<2;h++) aoff[s][h] = Ra*64 + 8*((lkb+4*h) ^ (Ra&7));
  }
  #pragma unroll
  for (int u=0;u<4;u++){
    const int Rb = wc + u*16 + l15;
    #pragma unroll
    for (int h=0;h<2;h++) boff[u][h] = Rb*64 + 8*((lkb+4*h) ^ (Rb&7));
  }

  auto ldB = [&](int st, int py, int px, ushort8& lo, ushort8& hi){
    const int k = k0 + st*64;
    const int t = k>>9;
    const int dy = t/3, dx = t - dy*3;
    const int yy = py + dy - 1, xx = px + dx - 1;
    lo = (ushort8){}; hi = (ushort8){};
    if ((unsigned)yy < 16u && (unsigned)xx < 32u){
      const unsigned short* b = XT + (size_t)(yy*32+xx)*512 + (k&511) + skb*8;
      lo = *(const ushort8*)b; hi = *(const ushort8*)(b+32);
    }
  };

  constexpr int NST = KCH/64;
  f32x4 acc[2][4] = {};
  ushort8 ra0 = *(const ushort8*)gA;
  ushort8 ra1 = *(const ushort8*)(gA+32);
  ushort8 b00,b01,b10,b11;
  ldB(0, py0, px0, b00, b01);
  ldB(0, py1, px1, b10, b11);
  *(ushort8*)(&lA[0][soffA0]) = ra0;  *(ushort8*)(&lA[0][soffA1]) = ra1;
  *(ushort8*)(&lB[0][soffB00]) = b00; *(ushort8*)(&lB[0][soffB01]) = b01;
  *(ushort8*)(&lB[0][soffB10]) = b10; *(ushort8*)(&lB[0][soffB11]) = b11;
  if (NST > 1){
    ra0 = *(const ushort8*)(gA+64); ra1 = *(const ushort8*)(gA+96);
    ldB(1, py0, px0, b00, b01);
    ldB(1, py1, px1, b10, b11);
  }
  __syncthreads();
  for (int st=0; st<NST; ++st){
    const int cur = st&1;
    bf16x8 af[2][2], bfr[4][2];
    #pragma unroll
    for (int s=0;s<2;s++)
      #pragma unroll
      for (int h=0;h<2;h++) af[s][h] = *(const bf16x8*)(&lA[cur][aoff[s][h]]);
    #pragma unroll
    for (int u=0;u<4;u++)
      #pragma unroll
      for (int h=0;h<2;h++) bfr[u][h] = *(const bf16x8*)(&lB[cur][boff[u][h]]);
    if (st+1 < NST){
      const int nxt = cur^1;
      *(ushort8*)(&lA[nxt][soffA0]) = ra0;  *(ushort8*)(&lA[nxt][soffA1]) = ra1;
      *(ushort8*)(&lB[nxt][soffB00]) = b00; *(ushort8*)(&lB[nxt][soffB01]) = b01;
      *(ushort8*)(&lB[nxt][soffB10]) = b10; *(ushort8*)(&lB[nxt][soffB11]) = b11;
      if (st+2 < NST){
        ra0 = *(const ushort8*)(gA + (size_t)(st+2)*64);
        ra1 = *(const ushort8*)(gA + (size_t)(st+2)*64 + 32);
        ldB(st+2, py0, px0, b00, b01);
        ldB(st+2, py1, px1, b10, b11);
      }
    }
    #pragma unroll
    for (int h=0;h<2;h++)
      #pragma unroll
      for (int s=0;s<2;s++)
        #pragma unroll
        for (int u=0;u<4;u++)
          acc[s][u] = __builtin_amdgcn_mfma_f32_16x16x32_bf16(af[s][h], bfr[u][h], acc[s][u], 0,0,0);
    __syncthreads();
  }

  unsigned short* pbase = part + (size_t)blockIdx.z*262144;
  #pragma unroll
  for (int s=0;s<2;s++)
    #pragma unroll
    for (int u=0;u<4;u++){
      const int row = m0 + wr + s*16 + lkb*4;
      const int col = n0 + wc + u*16 + l15;
      #pragma unroll
      for (int r=0;r<4;r++)
        pbase[(size_t)(row+r)*512 + col] = f2bf(acc[s][u][r]);
    }
}

// ===== final reduce: bias + bf16 partials + residual =========================
__global__ __launch_bounds__(256) void k_reduce_final(const unsigned short* __restrict__ part,
    const float* __restrict__ bias, const float* __restrict__ res,
    float* __restrict__ y, int nchunks){
  const int i = blockIdx.x*256 + threadIdx.x;
  const int o = i>>7;
  const float b = bias[o];
  float4 a4 = {b,b,b,b};
  for (int s=0;s<nchunks;s++){
    const ushort4v v = ((const ushort4v*)part)[(size_t)s*65536 + i];
    a4.x += bf2f(v.x); a4.y += bf2f(v.y); a4.z += bf2f(v.z); a4.w += bf2f(v.w);
  }
  const float4 rv = ((const float4*)res)[i];
  a4.x += rv.x; a4.y += rv.y; a4.z += rv.z; a4.w += rv.w;
  ((float4*)y)[i] = a4;
}

extern "C" void kernel_launch(void* const* d_in, const int* in_sizes, int n_in,
                              void* d_out, int out_size, void* d_ws, size_t ws_size,
                              hipStream_t stream) {
  (void)in_sizes; (void)n_in; (void)out_size; (void)ws_size;
  const float* xin    = (const float*)d_in[0];
  const float* deg    = (const float*)d_in[1];
  const float* k1_w1  = (const float*)d_in[2];
  const float* k1_w2  = (const float*)d_in[3];
  const float* p1_w   = (const float*)d_in[4];
  const float* p1_b   = (const float*)d_in[5];
  const float* ca1_w1 = (const float*)d_in[6];
  const float* ca1_w2 = (const float*)d_in[7];
  const float* conv1_w= (const float*)d_in[8];
  const float* conv1_b= (const float*)d_in[9];
  const float* k2_w1  = (const float*)d_in[10];
  const float* k2_w2  = (const float*)d_in[11];
  const float* p2_w   = (const float*)d_in[12];
  const float* p2_b   = (const float*)d_in[13];
  const float* ca2_w1 = (const float*)d_in[14];
  const float* ca2_w2 = (const float*)d_in[15];
  const float* conv2_w= (const float*)d_in[16];
  const float* conv2_b= (const float*)d_in[17];
  float* out = (float*)d_out;

  const int NS = 18;                       // conv split-K chunks (KCH=256)

  // ---- workspace ----
  float* ws = (float*)d_ws;
  unsigned short* PART = (unsigned short*)ws;
  ws += (size_t)NS*131072;                 // 9.4 MB
  float* KP1  = ws;  ws += 36864;          // 8 jc x 512 c x 9 t
  float* KP2  = ws;  ws += 36864;
  float* ATT1 = ws;  ws += 262144;
  float* ATT2 = ws;  ws += 262144;
  unsigned short* DEGB = (unsigned short*)ws; ws += 131072;
  unsigned short* DEGT = (unsigned short*)ws; ws += 131072;
  unsigned short* K1B  = (unsigned short*)ws; ws += 131072;
  unsigned short* K2B  = (unsigned short*)ws; ws += 131072;
  unsigned short* P1B  = (unsigned short*)ws; ws += 131072;
  unsigned short* P2B  = (unsigned short*)ws; ws += 131072;
  unsigned short* CA1A = (unsigned short*)ws; ws += 16384;
  unsigned short* CA1B = (unsigned short*)ws; ws += 16384;
  unsigned short* CA2A = (unsigned short*)ws; ws += 16384;
  unsigned short* CA2B = (unsigned short*)ws; ws += 16384;
  unsigned short* DWLT = (unsigned short*)ws; ws += 131072;
  unsigned short* XT   = (unsigned short*)ws; ws += 131072;
  unsigned short* WB1  = (unsigned short*)ws; ws += 1179648;
  unsigned short* WB2  = (unsigned short*)ws; ws += 1179648;

  // 1. all weight packs
  k_pack_all<<<6272,256,0,stream>>>(k1_w1,k2_w1,p1_w,p2_w,
      ca1_w1,ca1_w2,ca2_w1,ca2_w2, deg, conv1_w, conv2_w,
      K1B,K2B,P1B,P2B, CA1A,CA1B,CA2A,CA2B, DEGB,DEGT, WB1,WB2);

  // 2. fused pre-phase: kern partials + attention maps (256 uniform blocks)
  k_prep<<<256,256,0,stream>>>(DEGB,DEGT, K1B,K2B, CA1A,CA2A, CA1B,CA2B,
      k1_w2,k2_w2, KP1,KP2, ATT1,ATT2);

  // 3. da_conv1 depthwise -> DWLT [px][ch] bf16
  k_dwconv<<<512,512,0,stream>>>(xin, KP1, DWLT);
  // 4. pointwise 1 (+bias+deg*att+lrelu) -> XT
  k_pw<<<dim3(16,16),256,0,stream>>>(P1B, DWLT, p1_b, deg, ATT1, XT);
  // 5. conv1 3x3 (64x128 tile, BK=64, split-K=18)
  k_mfma_conv<256><<<dim3(8,4,18),256,0,stream>>>(WB1, XT, PART);
  // 6. fused reduce+lrelu+depthwise (da_conv2) -> DWLT
  k_dwconv_red<<<512,512,0,stream>>>(PART, conv1_b, KP2, DWLT, NS);
  // 7. pointwise 2 -> XT
  k_pw<<<dim3(16,16),256,0,stream>>>(P2B, DWLT, p2_b, deg, ATT2, XT);
  // 8. conv2 3x3
  k_mfma_conv<256><<<dim3(8,4,18),256,0,stream>>>(WB2, XT, PART);
  // 9. final reduce + bias + residual
  k_reduce_final<<<256,256,0,stream>>>(PART, conv2_b, xin, out, NS);
}